// Round 1
// baseline (63.957 us; speedup 1.0000x reference)
//
#include <hip/hip_runtime.h>

// MixtureOfExpertsNet: B=8388608 rows, E=4 experts, H=16 hidden.
// pred[i] = sum_e(p_e * m_e * adj_e) / sum_e(p_e * m_e)   (softmax /s cancels)
//   adj_e = relu(b2_e + sum_h relu(x_e*W1_eh + b1_eh) * W2_eh)
//   p_e   = exp(logit_e - max_logit),  logit = x_filled @ Wg^T + bg
//   m_e   = !isnan(x_e), x_filled = m ? x : 0
// One row per thread; weights read via uniform (scalar-cache) loads.

__global__ __launch_bounds__(256) void moe_kernel(
    const float4* __restrict__ x,
    const float* __restrict__ Wg, const float* __restrict__ bg,
    const float* __restrict__ W1, const float* __restrict__ b1,
    const float* __restrict__ W2, const float* __restrict__ b2,
    float* __restrict__ out, int B)
{
    int i = blockIdx.x * blockDim.x + threadIdx.x;
    if (i >= B) return;

    float4 xv = x[i];
    float xr[4] = {xv.x, xv.y, xv.z, xv.w};

    float xf[4], msk[4];
#pragma unroll
    for (int e = 0; e < 4; ++e) {
        float xe = xr[e];
        bool ok = (xe == xe);            // !isnan
        xf[e]  = ok ? xe : 0.0f;
        msk[e] = ok ? 1.0f : 0.0f;
    }

    float adj[4], logit[4];
#pragma unroll
    for (int e = 0; e < 4; ++e) {
        float acc = b2[e];
#pragma unroll
        for (int h = 0; h < 16; ++h) {
            float t = fmaf(xf[e], W1[e * 16 + h], b1[e * 16 + h]);
            t = fmaxf(t, 0.0f);
            acc = fmaf(t, W2[e * 16 + h], acc);
        }
        adj[e] = fmaxf(acc, 0.0f);
        logit[e] = fmaf(xf[0], Wg[e * 4 + 0],
                   fmaf(xf[1], Wg[e * 4 + 1],
                   fmaf(xf[2], Wg[e * 4 + 2],
                   fmaf(xf[3], Wg[e * 4 + 3], bg[e]))));
    }

    float mx = fmaxf(fmaxf(logit[0], logit[1]), fmaxf(logit[2], logit[3]));

    float num = 0.0f, den = 0.0f;
#pragma unroll
    for (int e = 0; e < 4; ++e) {
        float p = __expf(logit[e] - mx) * msk[e];
        den += p;
        num = fmaf(p, adj[e], num);
    }

    float pred = num * __builtin_amdgcn_rcpf(den);
    out[i] = (den > 0.0f) ? pred : __builtin_nanf("");
}

extern "C" void kernel_launch(void* const* d_in, const int* in_sizes, int n_in,
                              void* d_out, int out_size, void* d_ws, size_t ws_size,
                              hipStream_t stream) {
    const float4* x  = (const float4*)d_in[0];
    const float*  Wg = (const float*)d_in[1];
    const float*  bg = (const float*)d_in[2];
    const float*  W1 = (const float*)d_in[3];
    const float*  b1 = (const float*)d_in[4];
    const float*  W2 = (const float*)d_in[5];
    const float*  b2 = (const float*)d_in[6];
    float* out = (float*)d_out;

    int B = in_sizes[0] / 4;
    int blocks = (B + 255) / 256;
    moe_kernel<<<blocks, 256, 0, stream>>>(x, Wg, bg, W1, b1, W2, b2, out, B);
}